// Round 1
// baseline (153.270 us; speedup 1.0000x reference)
//
#include <hip/hip_runtime.h>
#include <cfloat>
#include <cstdint>

// Sampler: out[row] = argmax_v( nan_to_num(logits)/max(temp,eps) + gumbel(u) )
//          or argmax_v( nan_to_num(logits) ) when temp <= eps.
// Tie-break: lowest index (numpy argmax semantics), encoded via packed u64 key.

#define TEMP_EPS 1e-6f

static constexpr int V      = 128256;
static constexpr int V4     = V / 4;        // 32064 float4 per row
static constexpr int SEGS   = 16;
static constexpr int SEG_V4 = V4 / SEGS;    // 2004 float4 per segment (exact)

__device__ __forceinline__ float nan_to_num_f(float x) {
    if (x != x) return 0.0f;                       // NaN -> 0
    if (fabsf(x) == INFINITY) return x > 0.0f ? FLT_MAX : -FLT_MAX;
    return x;
}

// Monotonic float->uint mapping; key = (mapped_val << 32) | ~index.
// 64-bit max picks: larger value; on equal value, smaller index.
__device__ __forceinline__ unsigned long long pack_key(float v, int idx) {
    unsigned u = __float_as_uint(v);
    u = (u & 0x80000000u) ? ~u : (u | 0x80000000u);
    return ((unsigned long long)u << 32) | (unsigned)(~(unsigned)idx);
}

__device__ __forceinline__ unsigned long long umax64(unsigned long long a,
                                                     unsigned long long b) {
    return a > b ? a : b;
}

__global__ __launch_bounds__(256) void sampler_partial_kernel(
    const float* __restrict__ logits,
    const float* __restrict__ temps,
    const float* __restrict__ u,
    unsigned long long* __restrict__ partials) {
    const int row = blockIdx.y;
    const int seg = blockIdx.x;

    const float temp = temps[row];
    const bool greedy = (temp <= TEMP_EPS);
    const float safe_temp = fmaxf(temp, TEMP_EPS);

    const float4* __restrict__ l4 = (const float4*)(logits + (size_t)row * V);
    const float4* __restrict__ u4 = (const float4*)(u + (size_t)row * V);

    const float UC_LO = 1e-10f;
    const float UC_HI = (float)(1.0 - 1e-7);   // matches np.float32(1.0 - 1e-7)

    unsigned long long key = 0ULL;  // below any real packed key

    const int seg_begin = seg * SEG_V4;
    const int seg_end   = seg_begin + SEG_V4;

    if (greedy) {
        for (int i = seg_begin + threadIdx.x; i < seg_end; i += 256) {
            float4 lv = l4[i];
            const int base = i * 4;
            float a = nan_to_num_f(lv.x);
            float b = nan_to_num_f(lv.y);
            float c = nan_to_num_f(lv.z);
            float d = nan_to_num_f(lv.w);
            key = umax64(key, pack_key(a, base + 0));
            key = umax64(key, pack_key(b, base + 1));
            key = umax64(key, pack_key(c, base + 2));
            key = umax64(key, pack_key(d, base + 3));
        }
    } else {
        for (int i = seg_begin + threadIdx.x; i < seg_end; i += 256) {
            float4 lv = l4[i];
            float4 uv = u4[i];
            const int base = i * 4;

            float l0 = nan_to_num_f(lv.x) / safe_temp;
            float l1 = nan_to_num_f(lv.y) / safe_temp;
            float l2 = nan_to_num_f(lv.z) / safe_temp;
            float l3 = nan_to_num_f(lv.w) / safe_temp;

            float c0 = fminf(fmaxf(uv.x, UC_LO), UC_HI);
            float c1 = fminf(fmaxf(uv.y, UC_LO), UC_HI);
            float c2 = fminf(fmaxf(uv.z, UC_LO), UC_HI);
            float c3 = fminf(fmaxf(uv.w, UC_LO), UC_HI);

            float g0 = -__logf(-__logf(c0));
            float g1 = -__logf(-__logf(c1));
            float g2 = -__logf(-__logf(c2));
            float g3 = -__logf(-__logf(c3));
            // NOTE: use precise logf, not __logf, for numpy-matching accuracy.
            g0 = -logf(-logf(c0));
            g1 = -logf(-logf(c1));
            g2 = -logf(-logf(c2));
            g3 = -logf(-logf(c3));

            key = umax64(key, pack_key(l0 + g0, base + 0));
            key = umax64(key, pack_key(l1 + g1, base + 1));
            key = umax64(key, pack_key(l2 + g2, base + 2));
            key = umax64(key, pack_key(l3 + g3, base + 3));
        }
    }

    // wave (64-lane) shuffle reduction
    for (int o = 32; o > 0; o >>= 1)
        key = umax64(key, __shfl_down(key, o));

    __shared__ unsigned long long sdata[4];
    if ((threadIdx.x & 63) == 0) sdata[threadIdx.x >> 6] = key;
    __syncthreads();

    if (threadIdx.x == 0) {
        for (int w = 1; w < 4; ++w) key = umax64(key, sdata[w]);
        partials[row * SEGS + seg] = key;
    }
}

__global__ __launch_bounds__(64) void sampler_reduce_kernel(
    const unsigned long long* __restrict__ partials,
    int* __restrict__ out) {
    const int row = blockIdx.x;
    const int t = threadIdx.x;
    unsigned long long key = (t < SEGS) ? partials[row * SEGS + t] : 0ULL;
    for (int o = 32; o > 0; o >>= 1)
        key = umax64(key, __shfl_down(key, o));
    if (t == 0)
        out[row] = (int)(~(unsigned)(key & 0xFFFFFFFFull));
}

extern "C" void kernel_launch(void* const* d_in, const int* in_sizes, int n_in,
                              void* d_out, int out_size, void* d_ws, size_t ws_size,
                              hipStream_t stream) {
    const float* logits = (const float*)d_in[0];
    const float* temps  = (const float*)d_in[1];
    const float* u      = (const float*)d_in[2];
    int* out = (int*)d_out;
    const int B = in_sizes[1];   // 128 rows

    unsigned long long* partials = (unsigned long long*)d_ws;  // B*SEGS*8 = 16 KB

    dim3 grid1(SEGS, B);
    hipLaunchKernelGGL(sampler_partial_kernel, grid1, dim3(256), 0, stream,
                       logits, temps, u, partials);
    hipLaunchKernelGGL(sampler_reduce_kernel, dim3(B), dim3(64), 0, stream,
                       partials, out);
}

// Round 2
// 148.554 us; speedup vs baseline: 1.0317x; 1.0317x over previous
//
#include <hip/hip_runtime.h>
#include <cfloat>
#include <cstdint>

// Sampler: out[row] = argmax_v( nan_to_num(logits)/max(temp,eps) + gumbel(u) )
//          or argmax_v( nan_to_num(logits) ) when temp <= eps.
// Tie-break: lowest index (numpy argmax semantics) via packed u64 key.
//
// NUMERICS ARE FROZEN from round 1 (absmax 0.0 vs numpy): nan_to_num ->
// IEEE division by safe_temp -> clamp -> precise logf twice -> add.
// This round only changes memory structure (load hoisting, more blocks).

#define TEMP_EPS 1e-6f

static constexpr int V       = 128256;
static constexpr int V4      = V / 4;          // 32064 float4 per row
static constexpr int SEGS    = 32;
static constexpr int SEG_V4  = V4 / SEGS;      // 1002 float4 per segment (exact)
static constexpr int TAIL    = SEG_V4 - 3 * 256;  // 234

__device__ __forceinline__ float nan_to_num_f(float x) {
    if (x != x) return 0.0f;                     // NaN -> 0
    return fminf(fmaxf(x, -FLT_MAX), FLT_MAX);   // +-Inf -> +-FLT_MAX
}

// Monotonic float->uint mapping; key = (mapped_val << 32) | ~index.
// 64-bit max picks: larger value; on equal value, smaller index.
__device__ __forceinline__ unsigned long long pack_key(float v, int idx) {
    unsigned b = __float_as_uint(v);
    unsigned mask = (unsigned)(((int)b >> 31)) | 0x80000000u;  // neg: ~b, pos: b|sign
    b ^= mask;
    return ((unsigned long long)b << 32) | (unsigned)(~(unsigned)idx);
}

__device__ __forceinline__ unsigned long long umax64(unsigned long long a,
                                                     unsigned long long b) {
    return a > b ? a : b;
}

__global__ __launch_bounds__(256) void sampler_partial_kernel(
    const float* __restrict__ logits,
    const float* __restrict__ temps,
    const float* __restrict__ u,
    unsigned long long* __restrict__ partials) {
    const int row = blockIdx.y;
    const int seg = blockIdx.x;
    const int tid = threadIdx.x;

    const float temp = temps[row];
    const bool greedy = (temp <= TEMP_EPS);
    const float safe_temp = fmaxf(temp, TEMP_EPS);

    const float4* __restrict__ l4 = (const float4*)(logits + (size_t)row * V);
    const float4* __restrict__ u4 = (const float4*)(u + (size_t)row * V);

    const float UC_LO = 1e-10f;
    const float UC_HI = (float)(1.0 - 1e-7);

    const int base = seg * SEG_V4;

    // 3 full strided iterations + tail. Tail threads past TAIL re-read
    // element idx[0]: its candidates are already in the max, so the
    // duplicate is harmless and the compute stays branchless.
    int idx[4];
    idx[0] = base + tid;
    idx[1] = base + 256 + tid;
    idx[2] = base + 512 + tid;
    idx[3] = (tid < TAIL) ? (base + 768 + tid) : (base + tid);

    // Hoist ALL loads before any compute: 8 dwordx4 in flight per thread.
    float4 lv[4], uv[4];
#pragma unroll
    for (int k = 0; k < 4; ++k) lv[k] = l4[idx[k]];
#pragma unroll
    for (int k = 0; k < 4; ++k) uv[k] = u4[idx[k]];

    unsigned long long key = 0ULL;

    if (greedy) {
#pragma unroll
        for (int k = 0; k < 4; ++k) {
            const int e = idx[k] * 4;
            float a = nan_to_num_f(lv[k].x);
            float b = nan_to_num_f(lv[k].y);
            float c = nan_to_num_f(lv[k].z);
            float d = nan_to_num_f(lv[k].w);
            key = umax64(key, pack_key(a, e + 0));
            key = umax64(key, pack_key(b, e + 1));
            key = umax64(key, pack_key(c, e + 2));
            key = umax64(key, pack_key(d, e + 3));
        }
    } else {
#pragma unroll
        for (int k = 0; k < 4; ++k) {
            const int e = idx[k] * 4;

            float l0 = nan_to_num_f(lv[k].x) / safe_temp;
            float l1 = nan_to_num_f(lv[k].y) / safe_temp;
            float l2 = nan_to_num_f(lv[k].z) / safe_temp;
            float l3 = nan_to_num_f(lv[k].w) / safe_temp;

            float c0 = fminf(fmaxf(uv[k].x, UC_LO), UC_HI);
            float c1 = fminf(fmaxf(uv[k].y, UC_LO), UC_HI);
            float c2 = fminf(fmaxf(uv[k].z, UC_LO), UC_HI);
            float c3 = fminf(fmaxf(uv[k].w, UC_LO), UC_HI);

            float g0 = -logf(-logf(c0));
            float g1 = -logf(-logf(c1));
            float g2 = -logf(-logf(c2));
            float g3 = -logf(-logf(c3));

            key = umax64(key, pack_key(l0 + g0, e + 0));
            key = umax64(key, pack_key(l1 + g1, e + 1));
            key = umax64(key, pack_key(l2 + g2, e + 2));
            key = umax64(key, pack_key(l3 + g3, e + 3));
        }
    }

    // wave (64-lane) shuffle reduction
    for (int o = 32; o > 0; o >>= 1)
        key = umax64(key, __shfl_down(key, o));

    __shared__ unsigned long long sdata[4];
    if ((tid & 63) == 0) sdata[tid >> 6] = key;
    __syncthreads();

    if (tid == 0) {
        for (int w = 1; w < 4; ++w) key = umax64(key, sdata[w]);
        partials[row * SEGS + seg] = key;
    }
}

__global__ __launch_bounds__(64) void sampler_reduce_kernel(
    const unsigned long long* __restrict__ partials,
    int* __restrict__ out) {
    const int row = blockIdx.x;
    const int t = threadIdx.x;
    unsigned long long key = (t < SEGS) ? partials[row * SEGS + t] : 0ULL;
    for (int o = 32; o > 0; o >>= 1)
        key = umax64(key, __shfl_down(key, o));
    if (t == 0)
        out[row] = (int)(~(unsigned)(key & 0xFFFFFFFFull));
}

extern "C" void kernel_launch(void* const* d_in, const int* in_sizes, int n_in,
                              void* d_out, int out_size, void* d_ws, size_t ws_size,
                              hipStream_t stream) {
    const float* logits = (const float*)d_in[0];
    const float* temps  = (const float*)d_in[1];
    const float* u      = (const float*)d_in[2];
    int* out = (int*)d_out;
    const int B = in_sizes[1];   // 128 rows

    unsigned long long* partials = (unsigned long long*)d_ws;  // B*SEGS*8 = 32 KB

    dim3 grid1(SEGS, B);
    hipLaunchKernelGGL(sampler_partial_kernel, grid1, dim3(256), 0, stream,
                       logits, temps, u, partials);
    hipLaunchKernelGGL(sampler_reduce_kernel, dim3(B), dim3(64), 0, stream,
                       partials, out);
}